// Round 1
// baseline (170.234 us; speedup 1.0000x reference)
//
#include <hip/hip_runtime.h>

// LinearGaussianTree on MI355X.
// Tree: DEPTH=12 -> 4095 nodes, root + 4094 non-root. M=128, NODE_SIZE=64 ->
// 8192 independent "rows". Per row: s_i = w_i * s_parent + (1-w_i)*SCALE*n_i.
// Outputs (fp32, concatenated flat): samples (8192 x 4095), ms (8192 x 4094),
// scales (8192 x 4094), columns in REVERSE level order (level 11 first,
// level 1 last, root as the final samples column).

constexpr int   kDepth   = 12;
constexpr int   kSize    = 4095;   // 2^12 - 1 total nodes
constexpr int   kRest    = 4094;   // non-root nodes
constexpr int   kRows    = 8192;   // M * NODE_SIZE
constexpr float kScale   = 0.1f;
constexpr int   kBlock   = 256;

__device__ __forceinline__ float sigmoidf_fast(float x) {
    return 1.0f / (1.0f + __expf(-x));
}

// Tiny pre-pass: per-column w = sigmoid(weights[i]), sc = (1-w)*SCALE.
// 4094 entries each -> stays hot in L2 for the main kernel.
__global__ __launch_bounds__(kBlock) void lgt_precompute(
    const float* __restrict__ weights,
    float* __restrict__ w_tab,
    float* __restrict__ sc_tab)
{
    int i = blockIdx.x * kBlock + threadIdx.x;
    if (i < kRest) {
        float w = sigmoidf_fast(weights[i]);
        w_tab[i]  = w;
        sc_tab[i] = (1.0f - w) * kScale;
    }
}

// One block per row. Row's samples staged in LDS (16.4 KB), levels walked
// sequentially (parent at level d-1 must exist before level d).
__global__ __launch_bounds__(kBlock) void lgt_main(
    const float* __restrict__ weights,   // fallback path
    const float* __restrict__ w_tab,     // may be null
    const float* __restrict__ sc_tab,    // may be null
    const float* __restrict__ noise_root,
    const float* __restrict__ noise_rest,
    float* __restrict__ samples,
    float* __restrict__ ms,
    float* __restrict__ scales,
    int use_tab)
{
    // LDS slot t (0..4093) = tree node t's sample; slot 4094 = root sample.
    __shared__ float s_lds[kSize];

    const int row = blockIdx.x;
    const int tid = threadIdx.x;

    const float* __restrict__ nr = noise_rest + (size_t)row * kRest;
    float* __restrict__ samp_row = samples + (size_t)row * kSize;
    float* __restrict__ ms_row   = ms      + (size_t)row * kRest;
    float* __restrict__ sc_row   = scales  + (size_t)row * kRest;

    if (tid == 0) {
        float r = noise_root[row];          // IN_SCALE == 1.0
        s_lds[kRest]   = r;                 // root slot
        samp_row[kRest] = r;                // samples column 4094
    }
    __syncthreads();

    int off = 0;
    for (int d = 1; d < kDepth; ++d) {
        const int n       = 1 << d;
        const int colbase = 4096 - (n << 1);          // 4096 - 2^(d+1)
        const int pbase   = (d == 1) ? kRest : (off - (n >> 1));

        for (int i = tid; i < n; i += kBlock) {
            const int idx = off + i;                  // tree index (weights/noise col)
            float w, sc;
            if (use_tab) {
                w  = w_tab[idx];
                sc = sc_tab[idx];
            } else {
                w  = sigmoidf_fast(weights[idx]);
                sc = (1.0f - w) * kScale;
            }
            const float par = s_lds[pbase + (i >> 1)];
            const float mv  = w * par;
            const float s   = fmaf(sc, nr[idx], mv);

            s_lds[idx] = s;

            const int col = colbase + i;
            samp_row[col] = s;
            ms_row[col]   = mv;
            sc_row[col]   = sc;
        }
        __syncthreads();
        off += n;
    }
}

extern "C" void kernel_launch(void* const* d_in, const int* in_sizes, int n_in,
                              void* d_out, int out_size, void* d_ws, size_t ws_size,
                              hipStream_t stream)
{
    const float* weights    = (const float*)d_in[0];
    const float* noise_root = (const float*)d_in[1];
    const float* noise_rest = (const float*)d_in[2];

    float* out     = (float*)d_out;
    float* samples = out;
    float* ms      = samples + (size_t)kRows * kSize;
    float* scales  = ms      + (size_t)kRows * kRest;

    const size_t tab_bytes = 2 * (size_t)kRest * sizeof(float);
    int use_tab = (d_ws != nullptr && ws_size >= tab_bytes) ? 1 : 0;

    float* w_tab  = nullptr;
    float* sc_tab = nullptr;
    if (use_tab) {
        w_tab  = (float*)d_ws;
        sc_tab = w_tab + kRest;
        lgt_precompute<<<(kRest + kBlock - 1) / kBlock, kBlock, 0, stream>>>(
            weights, w_tab, sc_tab);
    }

    lgt_main<<<kRows, kBlock, 0, stream>>>(
        weights, w_tab, sc_tab, noise_root, noise_rest,
        samples, ms, scales, use_tab);
}

// Round 2
// 144.120 us; speedup vs baseline: 1.1812x; 1.1812x over previous
//
#include <hip/hip_runtime.h>

// LinearGaussianTree, MI355X. 8192 independent rows; per row a 4095-node
// binary tree: s_i = w_i * s_parent + (1-w_i)*SCALE*noise_i.
// Outputs fp32 flat: samples (8192x4095), ms (8192x4094), scales (8192x4094),
// columns in reverse level order (level 11 first, root = samples col 4094).
//
// Key identity (column-ordered storage): parent_col = (child_col >> 1) + 2048.
// Structure: phase 1 = level walk (noise reads + LDS only, barrier per level),
// phase 2 = barrier-free float4-vectorized streaming of all 3 outputs with
// per-row alignment peeling (row strides 4095/4094 are not multiples of 4).

constexpr int   kDepth = 12;
constexpr int   kSize  = 4095;   // samples columns (incl. root at col 4094)
constexpr int   kRest  = 4094;   // ms/scales columns
constexpr int   kRows  = 8192;   // M * NODE_SIZE
constexpr float kScale = 0.1f;
constexpr int   kBlock = 256;

// Column-ordered sigmoid tables (zero-init BSS; rewritten every launch).
__device__ __align__(16) float g_wcol[4096];
__device__ __align__(16) float g_sccol[4096];

__global__ __launch_bounds__(kBlock) void lgt_precompute(
    const float* __restrict__ weights)
{
    int t = blockIdx.x * kBlock + threadIdx.x;   // tree index 0..4093
    if (t < kRest) {
        int d = 31 - __clz(t + 2);               // level of node t
        int c = t + 4098 - 3 * (1 << d);         // output column of node t
        float w = 1.0f / (1.0f + __expf(-weights[t]));
        g_wcol[c]  = w;
        g_sccol[c] = (1.0f - w) * kScale;
    }
}

__global__ __launch_bounds__(kBlock) void lgt_main(
    const float* __restrict__ noise_root,
    const float* __restrict__ noise_rest,
    float* __restrict__ samples,
    float* __restrict__ ms,
    float* __restrict__ scales)
{
    __shared__ float s[4096];                    // samples, column-ordered

    const int row = blockIdx.x;
    const int tid = threadIdx.x;
    const float* __restrict__ nr = noise_rest + (size_t)row * kRest;

    // ---- phase 1: build the tree in LDS ----
    if (tid == 0) s[4094] = noise_root[row];     // IN_SCALE == 1.0
    __syncthreads();

    if (tid < 2) {                               // level 1 (n=2), cols 4092/4093
        int c = 4092 + tid;
        s[c] = fmaf(g_sccol[c], nr[tid], g_wcol[c] * s[4094]);
    }
    __syncthreads();

    int off = 2;                                 // off_d = 2^d - 2
    for (int d = 2; d < kDepth; ++d) {
        const int n = 1 << d;
        const int colbase = 4096 - (n << 1);     // ≡ 0 (mod 4)
        for (int i0 = tid << 2; i0 < n; i0 += (kBlock << 2)) {
            const int c = colbase + i0;          // ≡ 0 (mod 4)
            const float4 w4  = *(const float4*)(g_wcol  + c);
            const float4 sc4 = *(const float4*)(g_sccol + c);
            // noise flat index row*4094 + off + i0 is even -> float2 aligned
            const float2 nz0 = *(const float2*)(nr + off + i0);
            const float2 nz1 = *(const float2*)(nr + off + i0 + 2);
            const int p = (c >> 1) + 2048;       // parent column (disjoint range)
            const float p0 = s[p], p1 = s[p + 1];
            float4 v;
            v.x = fmaf(sc4.x, nz0.x, w4.x * p0);
            v.y = fmaf(sc4.y, nz0.y, w4.y * p0);
            v.z = fmaf(sc4.z, nz1.x, w4.z * p1);
            v.w = fmaf(sc4.w, nz1.y, w4.w * p1);
            *(float4*)(s + c) = v;               // 16B-aligned ds_write_b128
        }
        __syncthreads();
        off += n;
    }

    // ---- phase 2: barrier-free streaming stores ----
    // 2a: samples (stride 4095)
    {
        const size_t rb = (size_t)row * (size_t)kSize;
        float* __restrict__ sr = samples + rb;
        const int h = (int)((4u - ((unsigned)rb & 3u)) & 3u);
        if (tid < h) sr[tid] = s[tid];
        const int nch = (kSize - h) >> 2;
        for (int k = tid; k < nch; k += kBlock) {
            const int c = h + (k << 2);
            float4 v;
            v.x = s[c]; v.y = s[c + 1]; v.z = s[c + 2]; v.w = s[c + 3];
            *(float4*)(sr + c) = v;              // rb + c ≡ 0 (mod 4)
        }
        const int done = h + (nch << 2);
        if (tid >= 8 && tid < 8 + (kSize - done)) {
            const int c = done + tid - 8;
            sr[c] = s[c];
        }
    }
    // 2bc: ms and scales (stride 4094, shared alignment phase; h ∈ {0,2})
    {
        const size_t rb = (size_t)row * (size_t)kRest;
        float* __restrict__ mr = ms + rb;
        float* __restrict__ cr = scales + rb;
        const int h = (int)((4u - ((unsigned)rb & 3u)) & 3u);
        if (tid < h) {
            const int c = tid;
            mr[c] = g_wcol[c] * s[(c >> 1) + 2048];
            cr[c] = g_sccol[c];
        }
        const int nch = (kRest - h) >> 2;
        for (int k = tid; k < nch; k += kBlock) {
            const int c = h + (k << 2);          // even -> float2 loads aligned
            const float2 wa = *(const float2*)(g_wcol  + c);
            const float2 wb = *(const float2*)(g_wcol  + c + 2);
            const float2 ca = *(const float2*)(g_sccol + c);
            const float2 cb = *(const float2*)(g_sccol + c + 2);
            const int p = (c >> 1) + 2048;
            const float p0 = s[p], p1 = s[p + 1];
            float4 mv, cv;
            mv.x = wa.x * p0; mv.y = wa.y * p0;
            mv.z = wb.x * p1; mv.w = wb.y * p1;
            cv.x = ca.x; cv.y = ca.y; cv.z = cb.x; cv.w = cb.y;
            *(float4*)(mr + c) = mv;             // rb + c ≡ 0 (mod 4)
            *(float4*)(cr + c) = cv;
        }
        const int done = h + (nch << 2);
        if (tid >= 8 && tid < 8 + (kRest - done)) {
            const int c = done + tid - 8;
            mr[c] = g_wcol[c] * s[(c >> 1) + 2048];
            cr[c] = g_sccol[c];
        }
    }
}

extern "C" void kernel_launch(void* const* d_in, const int* in_sizes, int n_in,
                              void* d_out, int out_size, void* d_ws, size_t ws_size,
                              hipStream_t stream)
{
    const float* weights    = (const float*)d_in[0];
    const float* noise_root = (const float*)d_in[1];
    const float* noise_rest = (const float*)d_in[2];

    float* out     = (float*)d_out;
    float* samples = out;
    float* ms      = samples + (size_t)kRows * kSize;
    float* scales  = ms      + (size_t)kRows * kRest;

    lgt_precompute<<<(kRest + kBlock - 1) / kBlock, kBlock, 0, stream>>>(weights);
    lgt_main<<<kRows, kBlock, 0, stream>>>(noise_root, noise_rest,
                                           samples, ms, scales);
}